// Round 7
// baseline (159.804 us; speedup 1.0000x reference)
//
#include <hip/hip_runtime.h>
#include <math.h>

typedef unsigned int uint;
typedef unsigned short ushort;
typedef __attribute__((ext_vector_type(8))) short short8;
typedef __attribute__((ext_vector_type(4))) float f32x4;

// Problem constants
#define BB  16384
#define DD  64
#define NT_ 128
#define NZ_ 2048
#define NJ_ 2049   // NZ+1

// workspace layout (float offsets)
#define BIAS_OFF 0         // fp32 [64]
#define SCS_OFF  64        // float4 [2048] = {cc, inv, q, 0}  (8192 floats)
#define CZ0_OFF  8256      // bf16 cz k0 [NZ][32]  (32768 floats)
#define CZ1_OFF  41024     // bf16 cz k1 [NZ][32]
#define WZT0_OFF 73792     // bf16 WzT k0 [NZ][32]
#define WZT1_OFF 106560    // bf16 WzT k1 [NZ][32]
#define WZBP_OFF 139328    // bf16 Wz packed [64 chunks][64 d][32 c] (65536 floats)
#define PART_OFF 204864    // fp32 partials [4][64][NJ_] = 524544
// end 729408 floats ~= 2.9 MB

__device__ __forceinline__ ushort f2b(float x) {
  uint u = __float_as_uint(x);
  uint r = (u + 0x7FFFu + ((u >> 16) & 1u)) >> 16;
  return (ushort)r;
}
__device__ __forceinline__ ushort f2b_tr(float x) {   // truncation: 1 VALU op
  return (ushort)(__float_as_uint(x) >> 16);
}
__device__ __forceinline__ float b2f(ushort h) {
  return __uint_as_float(((uint)h) << 16);
}

// ---------------------------------------------------------------------------
// Kernel 1 (stage 1): split-K partial sums of W_t = einsum('dij,i->dj').
__global__ __launch_bounds__(256) void k_wt1(
    const float* __restrict__ t, const float* __restrict__ ct,
    const float* __restrict__ lst, const float* __restrict__ W,
    float* __restrict__ part)   // [4][64][NJ_]
{
  __shared__ float ph[32];
  int tx = threadIdx.x;
  int d  = blockIdx.y;
  int ic = blockIdx.z;
  if (tx < 32) {
    int i = ic * 32 + tx;
    float r = fabsf(t[0] - ct[i]) * __expf(-lst[i]);
    ph[tx] = __expf(-r * r);
  }
  __syncthreads();
  int j = blockIdx.x * 256 + tx;
  if (j >= NJ_) return;
  const float* Wp = W + (size_t)d * NT_ * NJ_ + (size_t)(ic * 32) * NJ_ + j;
  float acc = 0.f;
#pragma unroll
  for (int k = 0; k < 32; ++k) acc += Wp[(size_t)k * NJ_] * ph[k];
  part[((size_t)ic * 64 + d) * NJ_ + j] = acc;
}

// ---------------------------------------------------------------------------
// Kernel 2 (stage 2): 256 blocks x 256 thr, 8 centres/block.
// Reduce partials -> Wt; emit packed bf16 tables + scs float4 + bias.
__global__ __launch_bounds__(256) void k_prep2(
    const float* __restrict__ part, const float* __restrict__ cz,
    const float* __restrict__ lsz,
    float* __restrict__ bias, float4* __restrict__ scs,
    ushort* __restrict__ czb0, ushort* __restrict__ czb1,
    ushort* __restrict__ wzt0, ushort* __restrict__ wzt1,
    ushort* __restrict__ wzbp)
{
  __shared__ float wt[64][9];   // [d][c_local]
  int tid = threadIdx.x;
  int cb0 = blockIdx.x * 8;
#pragma unroll
  for (int h = 0; h < 2; ++h) {
    int f = h * 256 + tid;      // 512 = 64 d x 8 c
    int d = f >> 3, c = f & 7;
    size_t idx = (size_t)d * NJ_ + cb0 + c;
    float s = part[idx] + part[(size_t)64 * NJ_ + idx]
            + part[(size_t)128 * NJ_ + idx] + part[(size_t)192 * NJ_ + idx];
    wt[d][c] = s;
    int cg = cb0 + c;
    wzbp[((size_t)(cg >> 5) * 64 + d) * 32 + (cg & 31)] = f2b(s);
  }
  if (blockIdx.x == 0 && tid < 64) {
    size_t idx = (size_t)tid * NJ_ + 2048;
    bias[tid] = part[idx] + part[(size_t)64 * NJ_ + idx]
              + part[(size_t)128 * NJ_ + idx] + part[(size_t)192 * NJ_ + idx];
  }
  __syncthreads();
  int cl = tid >> 5;            // centre within block 0..7
  int k  = tid & 31;            // 0..31
  int c  = cb0 + cl;
  float cv0 = cz[(size_t)c * DD + k];
  float cv1 = cz[(size_t)c * DD + 32 + k];
  czb0[(size_t)c * 32 + k] = f2b(cv0);
  czb1[(size_t)c * 32 + k] = f2b(cv1);
  float w0 = wt[k][cl], w1 = wt[32 + k][cl];
  wzt0[(size_t)c * 32 + k] = f2b(w0);
  wzt1[(size_t)c * 32 + k] = f2b(w1);
  float ca = cv0 * cv0 + cv1 * cv1;
  float qa = w0 * cv0 + w1 * cv1;
  qa += __shfl_xor(qa, 1);  ca += __shfl_xor(ca, 1);
  qa += __shfl_xor(qa, 2);  ca += __shfl_xor(ca, 2);
  qa += __shfl_xor(qa, 4);  ca += __shfl_xor(ca, 4);
  qa += __shfl_xor(qa, 8);  ca += __shfl_xor(ca, 8);
  qa += __shfl_xor(qa, 16); ca += __shfl_xor(ca, 16);
  if (k == 0) scs[c] = make_float4(ca, __expf(-2.f * lsz[c]), qa, 0.f);
}

// ---------------------------------------------------------------------------
// Main fused MFMA kernel — barrier-free K-loop, coalesced fragment loads.
// Block: 512 thr = 8 waves, 8-way c-split (256 centres/wave); BM=32 rows
// (2 M-tiles/wave). Grid 512, ~21.5 KB LDS -> 2 blocks/CU = 16 waves/CU.
// z loaded fp32 direct from input and packed to bf16 in-register.
#define PH_LD 40

__global__ __launch_bounds__(512) void k_fused(
    const float* __restrict__ z,     // [BB][64] fp32
    const ushort* __restrict__ czb0, const ushort* __restrict__ czb1,
    const ushort* __restrict__ wzt0, const ushort* __restrict__ wzt1,
    const ushort* __restrict__ wzbp,
    const float4* __restrict__ scs, const float* __restrict__ bias,
    float* __restrict__ out)
{
  __shared__ char smem[20480];   // phi [8][32][PH_LD] ushort  OR  eps [32][68] float
  __shared__ float dlr[8][32];
  ushort* phs = (ushort*)smem;
  float*  eps = (float*)smem;

  int tid  = threadIdx.x;
  int wv   = tid >> 6;           // wave = c-split group 0..7
  int lane = tid & 63;
  int lrow = lane & 15, quad = lane >> 4;
  int b0 = blockIdx.x * 32;

  // A-fragments (2 M-tiles x 2 k-halves) from fp32 z, packed in-register
  short8 a[2][2];
#pragma unroll
  for (int mt = 0; mt < 2; ++mt) {
    const float* zr = z + (size_t)(b0 + mt * 16 + lrow) * DD;
#pragma unroll
    for (int hf = 0; hf < 2; ++hf) {
      float4 u0 = *(const float4*)(zr + hf * 32 + quad * 8);
      float4 u1 = *(const float4*)(zr + hf * 32 + quad * 8 + 4);
      short8 o;
      o[0] = (short)f2b(u0.x); o[1] = (short)f2b(u0.y);
      o[2] = (short)f2b(u0.z); o[3] = (short)f2b(u0.w);
      o[4] = (short)f2b(u1.x); o[5] = (short)f2b(u1.y);
      o[6] = (short)f2b(u1.z); o[7] = (short)f2b(u1.w);
      a[mt][hf] = o;
    }
  }
  // zz per row from bf16 fragments (consistent with the MFMA dot) + reduce
  float zzr[2][4];
#pragma unroll
  for (int mt = 0; mt < 2; ++mt) {
    float p = 0.f;
#pragma unroll
    for (int k = 0; k < 8; ++k) {
      float v0 = b2f((ushort)a[mt][0][k]), v1 = b2f((ushort)a[mt][1][k]);
      p += v0 * v0 + v1 * v1;
    }
    p += __shfl_xor(p, 16);
    p += __shfl_xor(p, 32);      // lane holds zz[row mt*16 + (lane&15)]
#pragma unroll
    for (int i = 0; i < 4; ++i) zzr[mt][i] = __shfl(p, quad * 4 + i);
  }

  f32x4 acc[2][4];
#pragma unroll
  for (int mt = 0; mt < 2; ++mt)
#pragma unroll
    for (int nt = 0; nt < 4; ++nt) acc[mt][nt] = (f32x4){0.f, 0.f, 0.f, 0.f};
  float dl[2][4] = {{0.f}};

  const f32x4 zero = (f32x4){0.f, 0.f, 0.f, 0.f};
  int cbase = wv * 256;
  int pbase = wv * 32 * PH_LD;
  for (int cc0 = 0; cc0 < 256; cc0 += 32) {
    int c0 = cbase + cc0;
    // ---- GEMM1 + elementwise (2 n-tiles of 16 centres) ----
#pragma unroll
    for (int nt = 0; nt < 2; ++nt) {
      int cg = c0 + nt * 16 + lrow;
      size_t ro = (size_t)cg * 32 + quad * 8;
      short8 bc0 = *(const short8*)(czb0 + ro);
      short8 bc1 = *(const short8*)(czb1 + ro);
      short8 bw0 = *(const short8*)(wzt0 + ro);
      short8 bw1 = *(const short8*)(wzt1 + ro);
      float4 sc = scs[cg];       // {cc, inv, q, 0}
#pragma unroll
      for (int mt = 0; mt < 2; ++mt) {
        f32x4 d1 = __builtin_amdgcn_mfma_f32_16x16x32_bf16(a[mt][0], bc0, zero, 0, 0, 0);
        d1       = __builtin_amdgcn_mfma_f32_16x16x32_bf16(a[mt][1], bc1, d1,   0, 0, 0);
        f32x4 d2 = __builtin_amdgcn_mfma_f32_16x16x32_bf16(a[mt][0], bw0, zero, 0, 0, 0);
        d2       = __builtin_amdgcn_mfma_f32_16x16x32_bf16(a[mt][1], bw1, d2,   0, 0, 0);
#pragma unroll
        for (int i = 0; i < 4; ++i) {
          float s = zzr[mt][i] + sc.x - 2.f * d1[i];
          s = fmaxf(s, 0.f);
          float p = __expf(-s * sc.y);
          dl[mt][i] += p * sc.y * (d2[i] - sc.z);
          phs[pbase + (mt * 16 + quad * 4 + i) * PH_LD + nt * 16 + lrow] = f2b_tr(p);
        }
      }
    }
    // ---- GEMM2: dz += phi @ Wz (B from packed chunk table, coalesced) ----
    short8 ap0 = *(const short8*)&phs[pbase + lrow * PH_LD + quad * 8];
    short8 ap1 = *(const short8*)&phs[pbase + (16 + lrow) * PH_LD + quad * 8];
    size_t cb = (size_t)(c0 >> 5) * 64 * 32;
#pragma unroll
    for (int nt = 0; nt < 4; ++nt) {
      short8 bb = *(const short8*)(wzbp + cb + (size_t)(nt * 16 + lrow) * 32 + quad * 8);
      acc[0][nt] = __builtin_amdgcn_mfma_f32_16x16x32_bf16(ap0, bb, acc[0][nt], 0, 0, 0);
      acc[1][nt] = __builtin_amdgcn_mfma_f32_16x16x32_bf16(ap1, bb, acc[1][nt], 0, 0, 0);
    }
  }

  // ---- dl partials (dlr not unioned; safe before combine barriers) ----
#pragma unroll
  for (int mt = 0; mt < 2; ++mt)
#pragma unroll
    for (int i = 0; i < 4; ++i) {
      float v = dl[mt][i];
      v += __shfl_xor(v, 1);
      v += __shfl_xor(v, 2);
      v += __shfl_xor(v, 4);
      v += __shfl_xor(v, 8);
      if (lrow == 0) dlr[wv][mt * 16 + quad * 4 + i] = v;
    }

  // ---- dz combine across the 8 c-split waves (eps reuses phi LDS) ----
  for (int s = 0; s < 8; ++s) {
    __syncthreads();
    if (wv == s) {
#pragma unroll
      for (int mt = 0; mt < 2; ++mt)
#pragma unroll
        for (int nt = 0; nt < 4; ++nt)
#pragma unroll
          for (int i = 0; i < 4; ++i) {
            int r = mt * 16 + quad * 4 + i;
            int d = nt * 16 + lrow;
            if (s == 0) eps[r * 68 + d] = acc[mt][nt][i];
            else        eps[r * 68 + d] += acc[mt][nt][i];
          }
    }
  }
  __syncthreads();

  // ---- outputs ----
  {
    int r = tid >> 4, d0 = (tid & 15) * 4;   // 512 thr x 4 floats = 32x64
    float4 e  = *(const float4*)&eps[r * 68 + d0];
    float4 bv = *(const float4*)&bias[d0];
    float4 o;
    o.x = e.x + bv.x; o.y = e.y + bv.y; o.z = e.z + bv.z; o.w = e.w + bv.w;
    *(float4*)&out[(size_t)(b0 + r) * DD + d0] = o;
  }
  if (tid < 32) {
    float s = 0.f;
#pragma unroll
    for (int k = 0; k < 8; ++k) s += dlr[k][tid];
    out[(size_t)BB * DD + b0 + tid] = 2.f * s;
  }
}

// ---------------------------------------------------------------------------
extern "C" void kernel_launch(void* const* d_in, const int* in_sizes, int n_in,
                              void* d_out, int out_size, void* d_ws, size_t ws_size,
                              hipStream_t stream)
{
  const float* t   = (const float*)d_in[0];
  const float* z   = (const float*)d_in[1];
  // d_in[2] = logp_z (unused)
  const float* cz  = (const float*)d_in[3];
  const float* lsz = (const float*)d_in[4];
  const float* ct  = (const float*)d_in[5];
  const float* lst = (const float*)d_in[6];
  const float* W   = (const float*)d_in[7];
  float* out = (float*)d_out;
  float* ws  = (float*)d_ws;

  float*  bias = ws + BIAS_OFF;
  float4* scs  = (float4*)(ws + SCS_OFF);
  ushort* czb0 = (ushort*)(ws + CZ0_OFF);
  ushort* czb1 = (ushort*)(ws + CZ1_OFF);
  ushort* wzt0 = (ushort*)(ws + WZT0_OFF);
  ushort* wzt1 = (ushort*)(ws + WZT1_OFF);
  ushort* wzbp = (ushort*)(ws + WZBP_OFF);
  float*  part = ws + PART_OFF;

  k_wt1<<<dim3(9, 64, 4), 256, 0, stream>>>(t, ct, lst, W, part);
  k_prep2<<<dim3(256), 256, 0, stream>>>(part, cz, lsz, bias, scs,
                                         czb0, czb1, wzt0, wzt1, wzbp);
  k_fused<<<dim3(BB / 32), 512, 0, stream>>>(z, czb0, czb1, wzt0, wzt1,
                                             wzbp, scs, bias, out);
}

// Round 8
// 153.447 us; speedup vs baseline: 1.0414x; 1.0414x over previous
//
#include <hip/hip_runtime.h>
#include <math.h>

typedef unsigned int uint;
typedef unsigned short ushort;
typedef unsigned char uchar;
typedef __attribute__((ext_vector_type(4))) float f32x4;

// Problem constants
#define BB  16384
#define DD  64
#define NT_ 128
#define NZ_ 2048
#define NJ_ 2049   // NZ+1

// workspace layout (float offsets)
#define BIAS_OFF 0         // fp32 [64]
#define SCS_OFF  64        // float4 [2048] = {cc, inv, q, 0}
#define ZF8A_OFF 8256      // fp8 z k-half0 [BB][32]  (131072 float slots)
#define ZF8B_OFF 139328    // fp8 z k-half1 [BB][32]
#define ZZG_OFF  270400    // fp32 zz [BB]
#define CZ8A_OFF 286784    // fp8 cz k0 [NZ][32] (16384 floats)
#define CZ8B_OFF 303168    // fp8 cz k1 [NZ][32]
#define WZ8A_OFF 319552    // fp8 WzT k0 [NZ][32]
#define WZ8B_OFF 335936    // fp8 WzT k1 [NZ][32]
#define WZBP_OFF 352320    // fp8 Wz packed [64 chunks][64 d][32 c] (65536 floats... bytes/4)
#define PART_OFF 417856    // fp32 partials [4][64][NJ_] = 524544
// end 942400 floats ~= 3.8 MB

// ---------------- fp8 e4m3 (OCP) conversion helpers ----------------
#if __has_builtin(__builtin_amdgcn_cvt_pk_fp8_f32)
__device__ __forceinline__ uint pk4_fp8(float a, float b, float c, float d) {
  int v = __builtin_amdgcn_cvt_pk_fp8_f32(a, b, 0, false);
  v = __builtin_amdgcn_cvt_pk_fp8_f32(c, d, v, true);
  return (uint)v;
}
__device__ __forceinline__ uchar f8_1(float x) {
  return (uchar)(__builtin_amdgcn_cvt_pk_fp8_f32(x, x, 0, false) & 0xFF);
}
#else
__device__ __forceinline__ uint sw_f8(float x) {
  uint u = __float_as_uint(x);
  uint s = (u >> 24) & 0x80u;
  float ax = __uint_as_float(u & 0x7FFFFFFFu);
  if (!(ax >= 0.015625f)) return s;          // flush tiny / NaN -> signed zero
  if (ax >= 448.f) return s | 0x7Eu;
  uint q = __float_as_uint(ax);
  q += 0x7FFFFu + ((q >> 20) & 1u);          // RNE at mantissa bit 20
  uint e = (q >> 23) - 120u;                 // rebias (127 -> 7)
  return s | ((e & 0xFu) << 3) | ((q >> 20) & 7u);
}
__device__ __forceinline__ uchar f8_1(float x) { return (uchar)sw_f8(x); }
__device__ __forceinline__ uint pk4_fp8(float a, float b, float c, float d) {
  return sw_f8(a) | (sw_f8(b) << 8) | (sw_f8(c) << 16) | (sw_f8(d) << 24);
}
#endif

// ---------------------------------------------------------------------------
// Kernel 1 (stage 1): split-K partial sums of W_t = einsum('dij,i->dj').
__global__ __launch_bounds__(256) void k_wt1(
    const float* __restrict__ t, const float* __restrict__ ct,
    const float* __restrict__ lst, const float* __restrict__ W,
    float* __restrict__ part)   // [4][64][NJ_]
{
  __shared__ float ph[32];
  int tx = threadIdx.x;
  int d  = blockIdx.y;
  int ic = blockIdx.z;
  if (tx < 32) {
    int i = ic * 32 + tx;
    float r = fabsf(t[0] - ct[i]) * __expf(-lst[i]);
    ph[tx] = __expf(-r * r);
  }
  __syncthreads();
  int j = blockIdx.x * 256 + tx;
  if (j >= NJ_) return;
  const float* Wp = W + (size_t)d * NT_ * NJ_ + (size_t)(ic * 32) * NJ_ + j;
  float acc = 0.f;
#pragma unroll
  for (int k = 0; k < 32; ++k) acc += Wp[(size_t)k * NJ_] * ph[k];
  part[((size_t)ic * 64 + d) * NJ_ + j] = acc;
}

// ---------------------------------------------------------------------------
// Kernel 2 (stage 2): 256 blocks x 256 thr, 8 centres/block.
// Reduce partials -> Wt; emit fp8 tables + scs float4 + bias.
__global__ __launch_bounds__(256) void k_prep2(
    const float* __restrict__ part, const float* __restrict__ cz,
    const float* __restrict__ lsz,
    float* __restrict__ bias, float4* __restrict__ scs,
    uchar* __restrict__ cz8a, uchar* __restrict__ cz8b,
    uchar* __restrict__ wz8a, uchar* __restrict__ wz8b,
    uchar* __restrict__ wzbp8)
{
  __shared__ float wt[64][9];   // [d][c_local]
  int tid = threadIdx.x;
  int cb0 = blockIdx.x * 8;
#pragma unroll
  for (int h = 0; h < 2; ++h) {
    int f = h * 256 + tid;      // 512 = 64 d x 8 c
    int d = f >> 3, c = f & 7;
    size_t idx = (size_t)d * NJ_ + cb0 + c;
    float s = part[idx] + part[(size_t)64 * NJ_ + idx]
            + part[(size_t)128 * NJ_ + idx] + part[(size_t)192 * NJ_ + idx];
    wt[d][c] = s;
    int cg = cb0 + c;
    wzbp8[((size_t)(cg >> 5) * 64 + d) * 32 + (cg & 31)] = f8_1(s);
  }
  if (blockIdx.x == 0 && tid < 64) {
    size_t idx = (size_t)tid * NJ_ + 2048;
    bias[tid] = part[idx] + part[(size_t)64 * NJ_ + idx]
              + part[(size_t)128 * NJ_ + idx] + part[(size_t)192 * NJ_ + idx];
  }
  __syncthreads();
  int cl = tid >> 5;            // centre within block 0..7
  int k  = tid & 31;            // 0..31
  int c  = cb0 + cl;
  float cv0 = cz[(size_t)c * DD + k];
  float cv1 = cz[(size_t)c * DD + 32 + k];
  cz8a[(size_t)c * 32 + k] = f8_1(cv0);
  cz8b[(size_t)c * 32 + k] = f8_1(cv1);
  float w0 = wt[k][cl], w1 = wt[32 + k][cl];
  wz8a[(size_t)c * 32 + k] = f8_1(w0);
  wz8b[(size_t)c * 32 + k] = f8_1(w1);
  float ca = cv0 * cv0 + cv1 * cv1;
  float qa = w0 * cv0 + w1 * cv1;
  qa += __shfl_xor(qa, 1);  ca += __shfl_xor(ca, 1);
  qa += __shfl_xor(qa, 2);  ca += __shfl_xor(ca, 2);
  qa += __shfl_xor(qa, 4);  ca += __shfl_xor(ca, 4);
  qa += __shfl_xor(qa, 8);  ca += __shfl_xor(ca, 8);
  qa += __shfl_xor(qa, 16); ca += __shfl_xor(ca, 16);
  if (k == 0) scs[c] = make_float4(ca, __expf(-2.f * lsz[c]), qa, 0.f);
}

// ---------------------------------------------------------------------------
// Kernel 3: z -> fp8 k-half tables [r][32] + fp32 zz table
__global__ __launch_bounds__(256) void k_zbp(
    const float* __restrict__ z, uchar* __restrict__ zf8a,
    uchar* __restrict__ zf8b, float* __restrict__ zzg)
{
  int g = blockIdx.x * 256 + threadIdx.x;   // 0..131071
  int r = g >> 3, s8 = g & 7;               // 8 threads/row, 8 floats each
  const float4* zp = (const float4*)(z + (size_t)r * DD + s8 * 8);
  float4 v0 = zp[0], v1 = zp[1];
  uint lo = pk4_fp8(v0.x, v0.y, v0.z, v0.w);
  uint hi = pk4_fp8(v1.x, v1.y, v1.z, v1.w);
  uchar* dst = (s8 < 4 ? zf8a : zf8b) + (size_t)r * 32 + (s8 & 3) * 8;
  *(uint2*)dst = make_uint2(lo, hi);
  float ss = v0.x * v0.x + v0.y * v0.y + v0.z * v0.z + v0.w * v0.w
           + v1.x * v1.x + v1.y * v1.y + v1.z * v1.z + v1.w * v1.w;
  ss += __shfl_xor(ss, 1);
  ss += __shfl_xor(ss, 2);
  ss += __shfl_xor(ss, 4);
  if (s8 == 0) zzg[r] = ss;
}

// ---------------------------------------------------------------------------
// Main fused MFMA kernel — R6 skeleton, full fp8 fragments.
// Block: 256 thr = 4 waves = 4-way c-split; BM=32 rows, 2 M-tiles/wave.
// Grid 512. Barrier-free K-loop; ~9.2 KB LDS.
#define PH_LD 40   // bytes per phi row (32 + 8 pad)

__global__ __launch_bounds__(256) void k_fused(
    const uchar* __restrict__ zf8a, const uchar* __restrict__ zf8b,
    const float* __restrict__ zzg,
    const uchar* __restrict__ cz8a, const uchar* __restrict__ cz8b,
    const uchar* __restrict__ wz8a, const uchar* __restrict__ wz8b,
    const uchar* __restrict__ wzbp8,
    const float4* __restrict__ scs, const float* __restrict__ bias,
    float* __restrict__ out)
{
  __shared__ char smem[8704];    // phi [4][32][PH_LD] fp8 (5120 B)  OR  eps [32][68] f32
  __shared__ float dlr[4][32];
  uchar* phs = (uchar*)smem;
  float* eps = (float*)smem;

  int tid  = threadIdx.x;
  int ws   = tid >> 6;           // wave = c-split group 0..3
  int lane = tid & 63;
  int lrow = lane & 15, quad = lane >> 4;
  int b0 = blockIdx.x * 32;

  // A-fragments (2 M-tiles x 2 k-halves), coalesced 512 B segments
  long az[2][2];
#pragma unroll
  for (int mt = 0; mt < 2; ++mt) {
    size_t ro = (size_t)(b0 + mt * 16 + lrow) * 32 + quad * 8;
    az[mt][0] = *(const long*)(zf8a + ro);
    az[mt][1] = *(const long*)(zf8b + ro);
  }
  // zz per row from the fp32 table
  float zzr[2][4];
#pragma unroll
  for (int mt = 0; mt < 2; ++mt) {
    float v = zzg[b0 + mt * 16 + lrow];
#pragma unroll
    for (int i = 0; i < 4; ++i) zzr[mt][i] = __shfl(v, quad * 4 + i);
  }

  f32x4 acc[2][4];
#pragma unroll
  for (int mt = 0; mt < 2; ++mt)
#pragma unroll
    for (int nt = 0; nt < 4; ++nt) acc[mt][nt] = (f32x4){0.f, 0.f, 0.f, 0.f};
  float dl[2][4] = {{0.f}};

  const f32x4 zero = (f32x4){0.f, 0.f, 0.f, 0.f};
  int cbase = ws * 512;
  int pbase = ws * 32 * PH_LD;
  for (int cc0 = 0; cc0 < 512; cc0 += 32) {
    int c0 = cbase + cc0;
    // ---- GEMM1 + elementwise (2 n-tiles of 16 centres) ----
#pragma unroll
    for (int nt = 0; nt < 2; ++nt) {
      int cg = c0 + nt * 16 + lrow;
      size_t ro = (size_t)cg * 32 + quad * 8;
      long bc0 = *(const long*)(cz8a + ro);
      long bc1 = *(const long*)(cz8b + ro);
      long bw0 = *(const long*)(wz8a + ro);
      long bw1 = *(const long*)(wz8b + ro);
      float4 sc = scs[cg];       // {cc, inv, q, 0}
#pragma unroll
      for (int mt = 0; mt < 2; ++mt) {
        f32x4 d1 = __builtin_amdgcn_mfma_f32_16x16x32_fp8_fp8(az[mt][0], bc0, zero, 0, 0, 0);
        d1       = __builtin_amdgcn_mfma_f32_16x16x32_fp8_fp8(az[mt][1], bc1, d1,   0, 0, 0);
        f32x4 d2 = __builtin_amdgcn_mfma_f32_16x16x32_fp8_fp8(az[mt][0], bw0, zero, 0, 0, 0);
        d2       = __builtin_amdgcn_mfma_f32_16x16x32_fp8_fp8(az[mt][1], bw1, d2,   0, 0, 0);
#pragma unroll
        for (int i = 0; i < 4; ++i) {
          float s = zzr[mt][i] + sc.x - 2.f * d1[i];
          s = fmaxf(s, 0.f);
          float p = __expf(-s * sc.y);
          dl[mt][i] += p * sc.y * (d2[i] - sc.z);
          phs[pbase + (mt * 16 + quad * 4 + i) * PH_LD + nt * 16 + lrow] = f8_1(p);
        }
      }
    }
    // ---- GEMM2: dz += phi @ Wz (fp8 A from LDS, fp8 B from packed table) ----
    long ap0 = *(const long*)&phs[pbase + lrow * PH_LD + quad * 8];
    long ap1 = *(const long*)&phs[pbase + (16 + lrow) * PH_LD + quad * 8];
    size_t cb = (size_t)(c0 >> 5) * 64 * 32;
#pragma unroll
    for (int nt = 0; nt < 4; ++nt) {
      long bb = *(const long*)(wzbp8 + cb + (size_t)(nt * 16 + lrow) * 32 + quad * 8);
      acc[0][nt] = __builtin_amdgcn_mfma_f32_16x16x32_fp8_fp8(ap0, bb, acc[0][nt], 0, 0, 0);
      acc[1][nt] = __builtin_amdgcn_mfma_f32_16x16x32_fp8_fp8(ap1, bb, acc[1][nt], 0, 0, 0);
    }
  }

  // ---- dl partials (dlr not unioned; safe before combine barriers) ----
#pragma unroll
  for (int mt = 0; mt < 2; ++mt)
#pragma unroll
    for (int i = 0; i < 4; ++i) {
      float v = dl[mt][i];
      v += __shfl_xor(v, 1);
      v += __shfl_xor(v, 2);
      v += __shfl_xor(v, 4);
      v += __shfl_xor(v, 8);
      if (lrow == 0) dlr[ws][mt * 16 + quad * 4 + i] = v;
    }

  // ---- dz combine across the 4 c-split waves (eps reuses phi LDS) ----
  for (int s = 0; s < 4; ++s) {
    __syncthreads();
    if (ws == s) {
#pragma unroll
      for (int mt = 0; mt < 2; ++mt)
#pragma unroll
        for (int nt = 0; nt < 4; ++nt)
#pragma unroll
          for (int i = 0; i < 4; ++i) {
            int r = mt * 16 + quad * 4 + i;
            int d = nt * 16 + lrow;
            if (s == 0) eps[r * 68 + d] = acc[mt][nt][i];
            else        eps[r * 68 + d] += acc[mt][nt][i];
          }
    }
  }
  __syncthreads();

  // ---- outputs ----
  {
    int r = tid >> 3, d0 = (tid & 7) * 8;   // 256 thr x 8 floats = 32x64
    float4 e0 = *(const float4*)&eps[r * 68 + d0];
    float4 e1 = *(const float4*)&eps[r * 68 + d0 + 4];
    float4 bv0 = *(const float4*)&bias[d0];
    float4 bv1 = *(const float4*)&bias[d0 + 4];
    float4 o0, o1;
    o0.x = e0.x + bv0.x; o0.y = e0.y + bv0.y; o0.z = e0.z + bv0.z; o0.w = e0.w + bv0.w;
    o1.x = e1.x + bv1.x; o1.y = e1.y + bv1.y; o1.z = e1.z + bv1.z; o1.w = e1.w + bv1.w;
    *(float4*)&out[(size_t)(b0 + r) * DD + d0]     = o0;
    *(float4*)&out[(size_t)(b0 + r) * DD + d0 + 4] = o1;
  }
  if (tid < 32) {
    float s = dlr[0][tid] + dlr[1][tid] + dlr[2][tid] + dlr[3][tid];
    out[(size_t)BB * DD + b0 + tid] = 2.f * s;
  }
}

// ---------------------------------------------------------------------------
extern "C" void kernel_launch(void* const* d_in, const int* in_sizes, int n_in,
                              void* d_out, int out_size, void* d_ws, size_t ws_size,
                              hipStream_t stream)
{
  const float* t   = (const float*)d_in[0];
  const float* z   = (const float*)d_in[1];
  // d_in[2] = logp_z (unused)
  const float* cz  = (const float*)d_in[3];
  const float* lsz = (const float*)d_in[4];
  const float* ct  = (const float*)d_in[5];
  const float* lst = (const float*)d_in[6];
  const float* W   = (const float*)d_in[7];
  float* out = (float*)d_out;
  float* ws  = (float*)d_ws;

  float*  bias = ws + BIAS_OFF;
  float4* scs  = (float4*)(ws + SCS_OFF);
  uchar*  zf8a = (uchar*)(ws + ZF8A_OFF);
  uchar*  zf8b = (uchar*)(ws + ZF8B_OFF);
  float*  zzg  = ws + ZZG_OFF;
  uchar*  cz8a = (uchar*)(ws + CZ8A_OFF);
  uchar*  cz8b = (uchar*)(ws + CZ8B_OFF);
  uchar*  wz8a = (uchar*)(ws + WZ8A_OFF);
  uchar*  wz8b = (uchar*)(ws + WZ8B_OFF);
  uchar*  wzbp8 = (uchar*)(ws + WZBP_OFF);
  float*  part = ws + PART_OFF;

  k_wt1<<<dim3(9, 64, 4), 256, 0, stream>>>(t, ct, lst, W, part);
  k_prep2<<<dim3(256), 256, 0, stream>>>(part, cz, lsz, bias, scs,
                                         cz8a, cz8b, wz8a, wz8b, wzbp8);
  k_zbp<<<dim3(512), 256, 0, stream>>>(z, zf8a, zf8b, zzg);
  k_fused<<<dim3(BB / 32), 256, 0, stream>>>(zf8a, zf8b, zzg, cz8a, cz8b,
                                             wz8a, wz8b, wzbp8, scs, bias, out);
}

// Round 9
// 141.155 us; speedup vs baseline: 1.1321x; 1.0871x over previous
//
#include <hip/hip_runtime.h>
#include <math.h>

typedef unsigned int uint;
typedef unsigned short ushort;
typedef unsigned char uchar;
typedef __attribute__((ext_vector_type(4))) float f32x4;

// Problem constants
#define BB  16384
#define DD  64
#define NT_ 128
#define NZ_ 2048
#define NJ_ 2049   // NZ+1

// workspace layout (float offsets)
#define BIAS_OFF 0         // fp32 [64]
#define SCS_OFF  64        // float4 [2048] = {cc, inv, q, 0}
#define ZF8A_OFF 8256      // fp8 z k-half0 [BB][32]
#define ZF8B_OFF 139328    // fp8 z k-half1 [BB][32]
#define ZZG_OFF  270400    // fp32 zz [BB]
#define CZ8A_OFF 286784    // fp8 cz k0 [NZ][32]
#define CZ8B_OFF 303168    // fp8 cz k1 [NZ][32]
#define WZ8A_OFF 319552    // fp8 WzT k0 [NZ][32]
#define WZ8B_OFF 335936    // fp8 WzT k1 [NZ][32]
#define WZBP_OFF 352320    // fp8 Wz packed [64 chunks][64 d][32 c]
#define PART_OFF 417856    // fp32 partials [4][64][NJ_] = 524544
// end 942400 floats ~= 3.8 MB

// ---------------- fp8 e4m3 (OCP) conversion helpers ----------------
#if __has_builtin(__builtin_amdgcn_cvt_pk_fp8_f32)
__device__ __forceinline__ uint pk4_fp8(float a, float b, float c, float d) {
  int v = __builtin_amdgcn_cvt_pk_fp8_f32(a, b, 0, false);
  v = __builtin_amdgcn_cvt_pk_fp8_f32(c, d, v, true);
  return (uint)v;
}
__device__ __forceinline__ uchar f8_1(float x) {
  return (uchar)(__builtin_amdgcn_cvt_pk_fp8_f32(x, x, 0, false) & 0xFF);
}
#else
__device__ __forceinline__ uint sw_f8(float x) {
  uint u = __float_as_uint(x);
  uint s = (u >> 24) & 0x80u;
  float ax = __uint_as_float(u & 0x7FFFFFFFu);
  if (!(ax >= 0.015625f)) return s;          // flush tiny / NaN -> signed zero
  if (ax >= 448.f) return s | 0x7Eu;
  uint q = __float_as_uint(ax);
  q += 0x7FFFFu + ((q >> 20) & 1u);          // RNE at mantissa bit 20
  uint e = (q >> 23) - 120u;                 // rebias (127 -> 7)
  return s | ((e & 0xFu) << 3) | ((q >> 20) & 7u);
}
__device__ __forceinline__ uchar f8_1(float x) { return (uchar)sw_f8(x); }
__device__ __forceinline__ uint pk4_fp8(float a, float b, float c, float d) {
  return sw_f8(a) | (sw_f8(b) << 8) | (sw_f8(c) << 16) | (sw_f8(d) << 24);
}
#endif

// ---------------------------------------------------------------------------
// Kernel 1 (stage 1): split-K partial sums of W_t = einsum('dij,i->dj').
__global__ __launch_bounds__(256) void k_wt1(
    const float* __restrict__ t, const float* __restrict__ ct,
    const float* __restrict__ lst, const float* __restrict__ W,
    float* __restrict__ part)   // [4][64][NJ_]
{
  __shared__ float ph[32];
  int tx = threadIdx.x;
  int d  = blockIdx.y;
  int ic = blockIdx.z;
  if (tx < 32) {
    int i = ic * 32 + tx;
    float r = fabsf(t[0] - ct[i]) * __expf(-lst[i]);
    ph[tx] = __expf(-r * r);
  }
  __syncthreads();
  int j = blockIdx.x * 256 + tx;
  if (j >= NJ_) return;
  const float* Wp = W + (size_t)d * NT_ * NJ_ + (size_t)(ic * 32) * NJ_ + j;
  float acc = 0.f;
#pragma unroll
  for (int k = 0; k < 32; ++k) acc += Wp[(size_t)k * NJ_] * ph[k];
  part[((size_t)ic * 64 + d) * NJ_ + j] = acc;
}

// ---------------------------------------------------------------------------
// Kernel 2 (stage 2): 256 blocks x 256 thr, 8 centres/block.
__global__ __launch_bounds__(256) void k_prep2(
    const float* __restrict__ part, const float* __restrict__ cz,
    const float* __restrict__ lsz,
    float* __restrict__ bias, float4* __restrict__ scs,
    uchar* __restrict__ cz8a, uchar* __restrict__ cz8b,
    uchar* __restrict__ wz8a, uchar* __restrict__ wz8b,
    uchar* __restrict__ wzbp8)
{
  __shared__ float wt[64][9];   // [d][c_local]
  int tid = threadIdx.x;
  int cb0 = blockIdx.x * 8;
#pragma unroll
  for (int h = 0; h < 2; ++h) {
    int f = h * 256 + tid;      // 512 = 64 d x 8 c
    int d = f >> 3, c = f & 7;
    size_t idx = (size_t)d * NJ_ + cb0 + c;
    float s = part[idx] + part[(size_t)64 * NJ_ + idx]
            + part[(size_t)128 * NJ_ + idx] + part[(size_t)192 * NJ_ + idx];
    wt[d][c] = s;
    int cg = cb0 + c;
    wzbp8[((size_t)(cg >> 5) * 64 + d) * 32 + (cg & 31)] = f8_1(s);
  }
  if (blockIdx.x == 0 && tid < 64) {
    size_t idx = (size_t)tid * NJ_ + 2048;
    bias[tid] = part[idx] + part[(size_t)64 * NJ_ + idx]
              + part[(size_t)128 * NJ_ + idx] + part[(size_t)192 * NJ_ + idx];
  }
  __syncthreads();
  int cl = tid >> 5;            // centre within block 0..7
  int k  = tid & 31;            // 0..31
  int c  = cb0 + cl;
  float cv0 = cz[(size_t)c * DD + k];
  float cv1 = cz[(size_t)c * DD + 32 + k];
  cz8a[(size_t)c * 32 + k] = f8_1(cv0);
  cz8b[(size_t)c * 32 + k] = f8_1(cv1);
  float w0 = wt[k][cl], w1 = wt[32 + k][cl];
  wz8a[(size_t)c * 32 + k] = f8_1(w0);
  wz8b[(size_t)c * 32 + k] = f8_1(w1);
  float ca = cv0 * cv0 + cv1 * cv1;
  float qa = w0 * cv0 + w1 * cv1;
  qa += __shfl_xor(qa, 1);  ca += __shfl_xor(ca, 1);
  qa += __shfl_xor(qa, 2);  ca += __shfl_xor(ca, 2);
  qa += __shfl_xor(qa, 4);  ca += __shfl_xor(ca, 4);
  qa += __shfl_xor(qa, 8);  ca += __shfl_xor(ca, 8);
  qa += __shfl_xor(qa, 16); ca += __shfl_xor(ca, 16);
  if (k == 0) scs[c] = make_float4(ca, __expf(-2.f * lsz[c]), qa, 0.f);
}

// ---------------------------------------------------------------------------
// Kernel 3: z -> fp8 k-half tables [r][32] + fp32 zz table
__global__ __launch_bounds__(256) void k_zbp(
    const float* __restrict__ z, uchar* __restrict__ zf8a,
    uchar* __restrict__ zf8b, float* __restrict__ zzg)
{
  int g = blockIdx.x * 256 + threadIdx.x;   // 0..131071
  int r = g >> 3, s8 = g & 7;               // 8 threads/row, 8 floats each
  const float4* zp = (const float4*)(z + (size_t)r * DD + s8 * 8);
  float4 v0 = zp[0], v1 = zp[1];
  uint lo = pk4_fp8(v0.x, v0.y, v0.z, v0.w);
  uint hi = pk4_fp8(v1.x, v1.y, v1.z, v1.w);
  uchar* dst = (s8 < 4 ? zf8a : zf8b) + (size_t)r * 32 + (s8 & 3) * 8;
  *(uint2*)dst = make_uint2(lo, hi);
  float ss = v0.x * v0.x + v0.y * v0.y + v0.z * v0.z + v0.w * v0.w
           + v1.x * v1.x + v1.y * v1.y + v1.z * v1.z + v1.w * v1.w;
  ss += __shfl_xor(ss, 1);
  ss += __shfl_xor(ss, 2);
  ss += __shfl_xor(ss, 4);
  if (s8 == 0) zzg[r] = ss;
}

// ---------------------------------------------------------------------------
// Main fused MFMA kernel — fp8, software-pipelined K-loop.
// Block: 256 thr = 4 waves = 4-way c-split; BM=32 rows, 2 M-tiles/wave.
// Grid 512. Register double-buffered prefetch of ALL global fragments for
// chunk i+1 issued at top of chunk i; phi LDS double-buffered by parity so
// GEMM1(i+1) can hoist above GEMM2(i) with no LDS same-address hazard.
#define PH_LD 40   // bytes per phi row (32 + 8 pad)

__global__ __launch_bounds__(256) void k_fused(
    const uchar* __restrict__ zf8a, const uchar* __restrict__ zf8b,
    const float* __restrict__ zzg,
    const uchar* __restrict__ cz8a, const uchar* __restrict__ cz8b,
    const uchar* __restrict__ wz8a, const uchar* __restrict__ wz8b,
    const uchar* __restrict__ wzbp8,
    const float4* __restrict__ scs, const float* __restrict__ bias,
    float* __restrict__ out)
{
  __shared__ char smem[10240];   // phi [2][4][32][PH_LD] fp8  OR  eps [32][68] f32
  __shared__ float dlr[4][32];
  uchar* phs = (uchar*)smem;
  float* eps = (float*)smem;

  int tid  = threadIdx.x;
  int ws   = tid >> 6;           // wave = c-split group 0..3
  int lane = tid & 63;
  int lrow = lane & 15, quad = lane >> 4;
  int b0 = blockIdx.x * 32;

  // A-fragments (2 M-tiles x 2 k-halves), coalesced 512 B segments
  long az[2][2];
#pragma unroll
  for (int mt = 0; mt < 2; ++mt) {
    size_t ro = (size_t)(b0 + mt * 16 + lrow) * 32 + quad * 8;
    az[mt][0] = *(const long*)(zf8a + ro);
    az[mt][1] = *(const long*)(zf8b + ro);
  }
  // zz per row from the fp32 table
  float zzr[2][4];
#pragma unroll
  for (int mt = 0; mt < 2; ++mt) {
    float v = zzg[b0 + mt * 16 + lrow];
#pragma unroll
    for (int i = 0; i < 4; ++i) zzr[mt][i] = __shfl(v, quad * 4 + i);
  }

  f32x4 acc[2][4];
#pragma unroll
  for (int mt = 0; mt < 2; ++mt)
#pragma unroll
    for (int nt = 0; nt < 4; ++nt) acc[mt][nt] = (f32x4){0.f, 0.f, 0.f, 0.f};
  float dl[2][4] = {{0.f}};

  const f32x4 zero = (f32x4){0.f, 0.f, 0.f, 0.f};
  int cbase = ws * 512;
  int pbase = ws * 32 * PH_LD;   // within one parity bank

  // ---- register double-buffered prefetch state ----
  long Abc0[2][2], Abc1[2][2], Abw0[2][2], Abw1[2][2], Abb[2][4];
  float4 Asc[2][2];
#define LOADB(PAR, C0)                                                         \
  do {                                                                         \
    int c0_ = (C0);                                                            \
    _Pragma("unroll")                                                          \
    for (int nt = 0; nt < 2; ++nt) {                                           \
      int cg_ = c0_ + nt * 16 + lrow;                                          \
      size_t ro_ = (size_t)cg_ * 32 + quad * 8;                                \
      Abc0[PAR][nt] = *(const long*)(cz8a + ro_);                              \
      Abc1[PAR][nt] = *(const long*)(cz8b + ro_);                              \
      Abw0[PAR][nt] = *(const long*)(wz8a + ro_);                              \
      Abw1[PAR][nt] = *(const long*)(wz8b + ro_);                              \
      Asc[PAR][nt]  = scs[cg_];                                                \
    }                                                                          \
    size_t cb_ = (size_t)(c0_ >> 5) * 64 * 32;                                 \
    _Pragma("unroll")                                                          \
    for (int nt = 0; nt < 4; ++nt)                                             \
      Abb[PAR][nt] =                                                           \
          *(const long*)(wzbp8 + cb_ + (size_t)(nt * 16 + lrow) * 32 + quad * 8); \
  } while (0)

  LOADB(0, cbase);
#pragma unroll 2
  for (int it = 0; it < 16; ++it) {
    int par = it & 1;
    // prefetch next chunk (wraps to cbase on last iter -> always in-bounds)
    LOADB(par ^ 1, cbase + ((it + 1) & 15) * 32);

    int pb = par * (4 * 32 * PH_LD) + pbase;
    // ---- GEMM1 + elementwise (2 n-tiles of 16 centres) ----
#pragma unroll
    for (int nt = 0; nt < 2; ++nt) {
      float4 sc = Asc[par][nt];       // {cc, inv, q, 0}
#pragma unroll
      for (int mt = 0; mt < 2; ++mt) {
        f32x4 d1 = __builtin_amdgcn_mfma_f32_16x16x32_fp8_fp8(az[mt][0], Abc0[par][nt], zero, 0, 0, 0);
        d1       = __builtin_amdgcn_mfma_f32_16x16x32_fp8_fp8(az[mt][1], Abc1[par][nt], d1,   0, 0, 0);
        f32x4 d2 = __builtin_amdgcn_mfma_f32_16x16x32_fp8_fp8(az[mt][0], Abw0[par][nt], zero, 0, 0, 0);
        d2       = __builtin_amdgcn_mfma_f32_16x16x32_fp8_fp8(az[mt][1], Abw1[par][nt], d2,   0, 0, 0);
#pragma unroll
        for (int i = 0; i < 4; ++i) {
          float s = zzr[mt][i] + sc.x - 2.f * d1[i];
          s = fmaxf(s, 0.f);
          float p = __expf(-s * sc.y);
          dl[mt][i] += p * sc.y * (d2[i] - sc.z);
          phs[pb + (mt * 16 + quad * 4 + i) * PH_LD + nt * 16 + lrow] = f8_1(p);
        }
      }
    }
    // ---- GEMM2: dz += phi @ Wz ----
    long ap0 = *(const long*)&phs[pb + lrow * PH_LD + quad * 8];
    long ap1 = *(const long*)&phs[pb + (16 + lrow) * PH_LD + quad * 8];
#pragma unroll
    for (int nt = 0; nt < 4; ++nt) {
      acc[0][nt] = __builtin_amdgcn_mfma_f32_16x16x32_fp8_fp8(ap0, Abb[par][nt], acc[0][nt], 0, 0, 0);
      acc[1][nt] = __builtin_amdgcn_mfma_f32_16x16x32_fp8_fp8(ap1, Abb[par][nt], acc[1][nt], 0, 0, 0);
    }
  }
#undef LOADB

  // ---- dl partials (dlr not unioned; safe before combine barriers) ----
#pragma unroll
  for (int mt = 0; mt < 2; ++mt)
#pragma unroll
    for (int i = 0; i < 4; ++i) {
      float v = dl[mt][i];
      v += __shfl_xor(v, 1);
      v += __shfl_xor(v, 2);
      v += __shfl_xor(v, 4);
      v += __shfl_xor(v, 8);
      if (lrow == 0) dlr[ws][mt * 16 + quad * 4 + i] = v;
    }

  // ---- dz combine across the 4 c-split waves (eps reuses phi LDS) ----
  for (int s = 0; s < 4; ++s) {
    __syncthreads();
    if (ws == s) {
#pragma unroll
      for (int mt = 0; mt < 2; ++mt)
#pragma unroll
        for (int nt = 0; nt < 4; ++nt)
#pragma unroll
          for (int i = 0; i < 4; ++i) {
            int r = mt * 16 + quad * 4 + i;
            int d = nt * 16 + lrow;
            if (s == 0) eps[r * 68 + d] = acc[mt][nt][i];
            else        eps[r * 68 + d] += acc[mt][nt][i];
          }
    }
  }
  __syncthreads();

  // ---- outputs ----
  {
    int r = tid >> 3, d0 = (tid & 7) * 8;   // 256 thr x 8 floats = 32x64
    float4 e0 = *(const float4*)&eps[r * 68 + d0];
    float4 e1 = *(const float4*)&eps[r * 68 + d0 + 4];
    float4 bv0 = *(const float4*)&bias[d0];
    float4 bv1 = *(const float4*)&bias[d0 + 4];
    float4 o0, o1;
    o0.x = e0.x + bv0.x; o0.y = e0.y + bv0.y; o0.z = e0.z + bv0.z; o0.w = e0.w + bv0.w;
    o1.x = e1.x + bv1.x; o1.y = e1.y + bv1.y; o1.z = e1.z + bv1.z; o1.w = e1.w + bv1.w;
    *(float4*)&out[(size_t)(b0 + r) * DD + d0]     = o0;
    *(float4*)&out[(size_t)(b0 + r) * DD + d0 + 4] = o1;
  }
  if (tid < 32) {
    float s = dlr[0][tid] + dlr[1][tid] + dlr[2][tid] + dlr[3][tid];
    out[(size_t)BB * DD + b0 + tid] = 2.f * s;
  }
}

// ---------------------------------------------------------------------------
extern "C" void kernel_launch(void* const* d_in, const int* in_sizes, int n_in,
                              void* d_out, int out_size, void* d_ws, size_t ws_size,
                              hipStream_t stream)
{
  const float* t   = (const float*)d_in[0];
  const float* z   = (const float*)d_in[1];
  // d_in[2] = logp_z (unused)
  const float* cz  = (const float*)d_in[3];
  const float* lsz = (const float*)d_in[4];
  const float* ct  = (const float*)d_in[5];
  const float* lst = (const float*)d_in[6];
  const float* W   = (const float*)d_in[7];
  float* out = (float*)d_out;
  float* ws  = (float*)d_ws;

  float*  bias = ws + BIAS_OFF;
  float4* scs  = (float4*)(ws + SCS_OFF);
  uchar*  zf8a = (uchar*)(ws + ZF8A_OFF);
  uchar*  zf8b = (uchar*)(ws + ZF8B_OFF);
  float*  zzg  = ws + ZZG_OFF;
  uchar*  cz8a = (uchar*)(ws + CZ8A_OFF);
  uchar*  cz8b = (uchar*)(ws + CZ8B_OFF);
  uchar*  wz8a = (uchar*)(ws + WZ8A_OFF);
  uchar*  wz8b = (uchar*)(ws + WZ8B_OFF);
  uchar*  wzbp8 = (uchar*)(ws + WZBP_OFF);
  float*  part = ws + PART_OFF;

  k_wt1<<<dim3(9, 64, 4), 256, 0, stream>>>(t, ct, lst, W, part);
  k_prep2<<<dim3(256), 256, 0, stream>>>(part, cz, lsz, bias, scs,
                                         cz8a, cz8b, wz8a, wz8b, wzbp8);
  k_zbp<<<dim3(512), 256, 0, stream>>>(z, zf8a, zf8b, zzg);
  k_fused<<<dim3(BB / 32), 256, 0, stream>>>(zf8a, zf8b, zzg, cz8a, cz8b,
                                             wz8a, wz8b, wzbp8, scs, bias, out);
}